// Round 1
// baseline (372.198 us; speedup 1.0000x reference)
//
#include <hip/hip_runtime.h>
#include <hip/hip_bf16.h>

// Problem constants (B,L,H,D) = (8,2048,8,64); sample_k = u = 40.
#define BB 8
#define LL 2048
#define HH 8
#define DD 64
#define HD 512      // H*D
#define SK 40       // sample_k
#define UU 40       // top-u
#define NCHUNK 16   // key chunks for flash-decode
#define CHUNK 128   // keys per chunk

typedef float v4f __attribute__((ext_vector_type(4)));

// ---------------- workspace layout (bytes) ----------------
static const size_t OFF_M     = 0;                 // B*H*L floats   = 512 KB
static const size_t OFF_TOP   = 512ull * 1024;     // B*H*40 ints    = 10 KB
static const size_t OFF_VPART = 592ull * 1024;     // 8*B*H*64 floats= 128 KB
static const size_t OFF_MPART = 768ull * 1024;     // B*H*40*16      = 160 KB
static const size_t OFF_SPART = 960ull * 1024;     // B*H*40*16      = 160 KB
static const size_t OFF_OPART = 1152ull * 1024;    // B*H*40*16*64   = 10 MB

// butterfly-add via DPP (VALU pipe). ctrl must be an ICE -> template param.
template <int CTRL>
__device__ __forceinline__ float dpp_add(float x) {
    int yi = __builtin_amdgcn_mov_dpp(__float_as_int(x), CTRL, 0xF, 0xF, true);
    return x + __int_as_float(yi);
}

// ============ kernel A v4: M[b,h,q] = max_s - mean_s of Q.Ksample ============
// block = 128 = 8 heads x 16 lanes. v4: all 40 indices hoisted to SGPRs up
// front (no per-iteration idx->addr->load chain), explicit 10-deep register
// rotation so 10 K-row gathers stay in flight, launch_bounds(128,4) to raise
// the VGPR cap (v3.1's 52 VGPRs collapsed the pipeline to ~2 loads deep).
#define KA_PF 10
__global__ __launch_bounds__(128, 4) void kA_sample_scores(
    const float* __restrict__ Q, const float* __restrict__ K,
    const int* __restrict__ IS, float* __restrict__ M)
{
    int blk = blockIdx.x;
    int b = blk & 7;                 // XCD pin: batch b -> XCD b (K[b]=4MB==L2)
    int q = blk >> 3;
    int tid = threadIdx.x;
    int h = tid >> 4;
    int lane = tid & 15;

    const int* __restrict__ isq = IS + q * SK;   // block-uniform
    size_t base = (size_t)b * LL * HD;
    int off = h * DD + lane * 4;                 // per-thread, constant over s
    v4f qv = __builtin_nontemporal_load(
        (const v4f*)(Q + base + (size_t)q * HD + off));
    const float* __restrict__ Kb = K + base;

    // hoist all 40 indices into SGPRs (batched scalar loads, issued once)
    int sidx[SK];
#pragma unroll
    for (int s = 0; s < SK; ++s)
        sidx[s] = __builtin_amdgcn_readfirstlane(isq[s]);

    // prologue: fill 10-deep rotation buffer
    float4 kv[KA_PF];
#pragma unroll
    for (int i = 0; i < KA_PF; ++i)
        kv[i] = *(const float4*)(Kb + (size_t)sidx[i] * HD + off);

    float mx = -1e30f, sm = 0.f;
#pragma unroll
    for (int s = 0; s < SK; ++s) {
        float4 k = kv[s % KA_PF];
        if (s + KA_PF < SK)
            kv[s % KA_PF] = *(const float4*)(Kb + (size_t)sidx[s + KA_PF] * HD + off);
        float p = qv.x * k.x + qv.y * k.y + qv.z * k.z + qv.w * k.w;
        p = dpp_add<0xB1>(p);    // quad_perm xor1
        p = dpp_add<0x4E>(p);    // quad_perm xor2
        p = dpp_add<0x141>(p);   // row_half_mirror (== xor4 here)
        p = dpp_add<0x140>(p);   // row_mirror      (== xor8 here)
        mx = fmaxf(mx, p);
        sm += p;
    }
    if (lane == 0)
        M[((size_t)(b * HH + h)) * LL + q] = mx - sm * (1.0f / SK);
}

// ============ kernel B: top-40 of M[bh,:] via 3-level parallel radix select ============
__global__ __launch_bounds__(256) void kB_topk(
    const float* __restrict__ M, int* __restrict__ TopIdx)
{
    int bh = blockIdx.x;
    int tid = threadIdx.x;
    __shared__ unsigned keys[LL];        // 8 KB
    __shared__ int      hist[4096];      // 16 KB
    __shared__ int      sscan[256];      // 1 KB
    __shared__ unsigned ckeyA[2048];     // 8 KB
    __shared__ int      cidxA[2048];     // 8 KB
    __shared__ unsigned ckeyB[2048];     // 8 KB
    __shared__ int      cidxB[2048];     // 8 KB
    __shared__ int ctr[8]; // 0:sel 1:nA 2:nB 3:T 4:kprime 5:nExact

    const float* __restrict__ m = M + (size_t)bh * LL;
    for (int i = tid; i < 4096; i += 256) hist[i] = 0;
    if (tid < 8) ctr[tid] = 0;
    __syncthreads();

    // ---- L1 histogram (bits 31:20) ----
    for (int i = tid; i < LL; i += 256) {
        unsigned u = __float_as_uint(m[i]);
        u = (u & 0x80000000u) ? ~u : (u | 0x80000000u);   // monotone key
        keys[i] = u;
        atomicAdd(&hist[u >> 20], 1);
    }
    __syncthreads();
    // ---- L1 scan (target UU) ----
    {
        int p = 0;
#pragma unroll
        for (int j = 0; j < 16; ++j) p += hist[tid * 16 + j];
        sscan[tid] = p;
        __syncthreads();
        for (int o = 1; o < 256; o <<= 1) {
            int v = (tid + o < 256) ? sscan[tid + o] : 0;
            __syncthreads();
            sscan[tid] += v;
            __syncthreads();
        }
        int snext = (tid < 255) ? sscan[tid + 1] : 0;
        if (sscan[tid] >= UU && snext < UU) {
            int cum = snext;
            for (int bkt = tid * 16 + 15; bkt >= tid * 16; --bkt) {
                int c = hist[bkt];
                if (cum + c >= UU) { ctr[3] = bkt; ctr[4] = UU - cum; break; }
                cum += c;
            }
        }
    }
    __syncthreads();
    unsigned T1 = (unsigned)ctr[3];
    int k1 = ctr[4];
    // ---- L1 pass ----
    for (int i = tid; i < LL; i += 256) {
        unsigned u = keys[i];
        unsigned bkt = u >> 20;
        if (bkt > T1) {
            int p = atomicAdd(&ctr[0], 1);
            TopIdx[bh * UU + p] = i;
        } else if (bkt == T1) {
            int p = atomicAdd(&ctr[1], 1);
            ckeyA[p] = u; cidxA[p] = i;
        }
    }
    __syncthreads();
    int nA = ctr[1];

    // ---- L2 histogram (bits 19:8) ----
    for (int i = tid; i < 4096; i += 256) hist[i] = 0;
    __syncthreads();
    for (int i = tid; i < nA; i += 256)
        atomicAdd(&hist[(ckeyA[i] >> 8) & 0xFFF], 1);
    __syncthreads();
    // ---- L2 scan (target k1) ----
    {
        int p = 0;
#pragma unroll
        for (int j = 0; j < 16; ++j) p += hist[tid * 16 + j];
        sscan[tid] = p;
        __syncthreads();
        for (int o = 1; o < 256; o <<= 1) {
            int v = (tid + o < 256) ? sscan[tid + o] : 0;
            __syncthreads();
            sscan[tid] += v;
            __syncthreads();
        }
        int snext = (tid < 255) ? sscan[tid + 1] : 0;
        if (sscan[tid] >= k1 && snext < k1) {
            int cum = snext;
            for (int bkt = tid * 16 + 15; bkt >= tid * 16; --bkt) {
                int c = hist[bkt];
                if (cum + c >= k1) { ctr[3] = bkt; ctr[4] = k1 - cum; break; }
                cum += c;
            }
        }
    }
    __syncthreads();
    unsigned T2 = (unsigned)ctr[3];
    int k2 = ctr[4];
    // ---- L2 pass ----
    for (int i = tid; i < nA; i += 256) {
        unsigned u = ckeyA[i];
        unsigned bkt = (u >> 8) & 0xFFF;
        if (bkt > T2) {
            int p = atomicAdd(&ctr[0], 1);
            TopIdx[bh * UU + p] = cidxA[i];
        } else if (bkt == T2) {
            int p = atomicAdd(&ctr[2], 1);
            ckeyB[p] = u; cidxB[p] = cidxA[i];
        }
    }
    __syncthreads();
    int nB = ctr[2];

    // ---- L3 histogram (bits 7:0) ----
    for (int i = tid; i < 256; i += 256) hist[i] = 0;
    __syncthreads();
    for (int i = tid; i < nB; i += 256)
        atomicAdd(&hist[ckeyB[i] & 0xFF], 1);
    __syncthreads();
    // ---- L3 scan (target k2) ----
    {
        sscan[tid] = hist[tid];
        __syncthreads();
        for (int o = 1; o < 256; o <<= 1) {
            int v = (tid + o < 256) ? sscan[tid + o] : 0;
            __syncthreads();
            sscan[tid] += v;
            __syncthreads();
        }
        int snext = (tid < 255) ? sscan[tid + 1] : 0;
        if (sscan[tid] >= k2 && snext < k2) { ctr[3] = tid; ctr[4] = k2 - snext; }
    }
    __syncthreads();
    unsigned T3 = (unsigned)ctr[3];
    int k3 = ctr[4];
    // ---- L3 pass ----
    for (int i = tid; i < nB; i += 256) {
        unsigned u = ckeyB[i];
        unsigned bkt = u & 0xFF;
        if (bkt > T3) {
            int p = atomicAdd(&ctr[0], 1);
            TopIdx[bh * UU + p] = cidxB[i];
        } else if (bkt == T3) {
            int p = atomicAdd(&ctr[5], 1);
            cidxA[p] = cidxB[i];
        }
    }
    __syncthreads();
    // ---- exact-key ties: pick k3 smallest indices ----
    if (tid == 0) {
        int n = ctr[5];
        int basep = ctr[0];
        for (int r = 0; r < k3; ++r) {
            int bi = 1 << 30, bp = -1;
            for (int j = 0; j < n; ++j) {
                int id = cidxA[j];
                if (id >= 0 && id < bi) { bi = id; bp = j; }
            }
            TopIdx[bh * UU + basep + r] = bi;
            cidxA[bp] = -1;
        }
    }
}

// ============ kernel C: V partial column-sums (float4 coalesced) ============
__global__ __launch_bounds__(256) void kC_vmean(
    const float* __restrict__ V, float* __restrict__ Vpart)
{
    int bh = blockIdx.x >> 3;
    int ch = blockIdx.x & 7;
    int b = bh >> 3, h = bh & 7;
    int tid = threadIdx.x;
    int dq = tid & 15;
    int lg = tid >> 4;

    float4 acc = make_float4(0.f, 0.f, 0.f, 0.f);
    size_t base = ((size_t)b * LL + ch * 256) * HD + h * DD + dq * 4;
    for (int l = lg; l < 256; l += 16) {
        float4 v = *(const float4*)(V + base + (size_t)l * HD);
        acc.x += v.x; acc.y += v.y; acc.z += v.z; acc.w += v.w;
    }
    __shared__ float4 red[256];
    red[tid] = acc;
    __syncthreads();
    if (tid < 16) {
        float4 s = make_float4(0.f, 0.f, 0.f, 0.f);
#pragma unroll
        for (int g = 0; g < 16; ++g) {
            float4 v = red[g * 16 + tid];
            s.x += v.x; s.y += v.y; s.z += v.z; s.w += v.w;
        }
        *(float4*)(Vpart + ch * 4096 + bh * 64 + tid * 4) = s;
    }
}

// ============ kernel D: fill all output rows with mean(V)/L ============
__global__ __launch_bounds__(256) void kD_fill(
    const float* __restrict__ Vpart, float* __restrict__ out)
{
    size_t i4 = (size_t)blockIdx.x * 256 + threadIdx.x;
    size_t o = i4 * 4;
    int hd = (int)(o & (HD - 1));
    int b  = (int)(o >> 20);
    int h  = hd >> 6;
    int idx = (b * HH + h) * DD + (hd & 63);
    float4 acc = make_float4(0.f, 0.f, 0.f, 0.f);
#pragma unroll
    for (int c = 0; c < 8; ++c) {
        float4 v = *(const float4*)(Vpart + c * 4096 + idx);
        acc.x += v.x; acc.y += v.y; acc.z += v.z; acc.w += v.w;
    }
    const float sc = 1.0f / LL;
    float4 r; r.x = acc.x * sc; r.y = acc.y * sc; r.z = acc.z * sc; r.w = acc.w * sc;
    *(float4*)(out + o) = r;
}

// ============ kernel E v6: flash-decode partials ============
// Restructured to halve LDS-pipe pressure (the v5 bottleneck: 320 b128 + 384
// b32 LDS reads per thread ~ 6.1k LDS cyc/wave vs 2.6k VALU cyc):
//  - scores: each thread owns TWO key rows (l, l+64); one wave owns 10 u's.
//    Each Qs ds_read_b128 now feeds 8 FMAs (was 4) -> 160 reads/thread.
//    Softmax max/sum over all 128 keys is a single in-wave shfl butterfly --
//    no cross-wave LDS combine, fewer barriers.
//  - P stored transposed PT[u][l] (stride 132: 16B-aligned rows, broadcast
//    reads land 4 banks apart) so PV reads P as b128: 96 reads/thread
//    (was 384 scalar b32).
__global__ __launch_bounds__(256) void kE_attn_partial(
    const float* __restrict__ Q, const float* __restrict__ K, const float* __restrict__ V,
    const int* __restrict__ TopIdx,
    float* __restrict__ Opart, float* __restrict__ mpart, float* __restrict__ spart)
{
    int c  = blockIdx.x;
    int bh = blockIdx.y;
    int b = bh >> 3, h = bh & 7;
    int tid = threadIdx.x;

    __shared__ float Qs[UU * DD];            // 10 KB
    __shared__ float PT[UU][CHUNK + 4];      // 20.6 KB, transposed P, stride 132
    __shared__ int   qidx[UU];
    __shared__ float mred[UU], sred[UU];

    if (tid < UU) qidx[tid] = TopIdx[bh * UU + tid];
    __syncthreads();

    size_t hbase  = (size_t)b * LL * HD + h * DD;
    size_t kcbase = hbase + (size_t)c * CHUNK * HD;

    for (int r = tid; r < UU * 16; r += 256) {
        int u = r >> 4, j = r & 15;
        *(float4*)(Qs + u * DD + j * 4) =
            *(const float4*)(Q + hbase + (size_t)qidx[u] * HD + j * 4);
    }
    __syncthreads();

    // ---- scores + in-register softmax ----
    {
        int w = tid >> 6;            // wave id: owns u in [w*10, w*10+10)
        int lane = tid & 63;         // key rows l0=lane, l1=lane+64
        const float* __restrict__ K0 = K + kcbase + (size_t)lane * HD;
        const float* __restrict__ K1 = K0 + (size_t)64 * HD;

        float d0[10], d1[10];
#pragma unroll
        for (int i = 0; i < 10; ++i) { d0[i] = 0.f; d1[i] = 0.f; }

#pragma unroll
        for (int qt = 0; qt < 4; ++qt) {        // 16 floats of d per quarter
            float4 ka[4], kb[4];
#pragma unroll
            for (int j = 0; j < 4; ++j) {
                ka[j] = *(const float4*)(K0 + qt * 16 + j * 4);
                kb[j] = *(const float4*)(K1 + qt * 16 + j * 4);
            }
#pragma unroll
            for (int j = 0; j < 4; ++j) {
#pragma unroll
                for (int uu = 0; uu < 10; ++uu) {
                    float4 qv = *(const float4*)(Qs + (w * 10 + uu) * DD + qt * 16 + j * 4);
                    d0[uu] += qv.x * ka[j].x + qv.y * ka[j].y + qv.z * ka[j].z + qv.w * ka[j].w;
                    d1[uu] += qv.x * kb[j].x + qv.y * kb[j].y + qv.z * kb[j].z + qv.w * kb[j].w;
                }
            }
        }

#pragma unroll
        for (int uu = 0; uu < 10; ++uu) {
            int u = w * 10 + uu;
            float x0 = d0[uu] * 0.125f;          // 1/sqrt(64)
            float x1 = d1[uu] * 0.125f;
            float m = fmaxf(x0, x1);
            m = fmaxf(m, __shfl_xor(m, 1));
            m = fmaxf(m, __shfl_xor(m, 2));
            m = fmaxf(m, __shfl_xor(m, 4));
            m = fmaxf(m, __shfl_xor(m, 8));
            m = fmaxf(m, __shfl_xor(m, 16));
            m = fmaxf(m, __shfl_xor(m, 32));     // max over all 128 keys
            float p0 = __expf(x0 - m);
            float p1 = __expf(x1 - m);
            PT[u][lane]      = p0;
            PT[u][lane + 64] = p1;
            float s = p0 + p1;
            s += __shfl_xor(s, 1);
            s += __shfl_xor(s, 2);
            s += __shfl_xor(s, 4);
            s += __shfl_xor(s, 8);
            s += __shfl_xor(s, 16);
            s += __shfl_xor(s, 32);              // sum over all 128 keys
            if (lane == 0) { mred[u] = m; sred[u] = s; }
        }
    }
    __syncthreads();   // PT + mred/sred ready

    // ---- PV: thread (dq = tid&15 -> d=dq*4, ug4 = tid>>4); u = ug4 + 16i ----
    {
        int dq = tid & 15, ug4 = tid >> 4;
        float4 acc[3];
#pragma unroll
        for (int i = 0; i < 3; ++i) acc[i] = make_float4(0.f, 0.f, 0.f, 0.f);
        const float* __restrict__ Vb = V + kcbase + dq * 4;
        for (int l0 = 0; l0 < CHUNK; l0 += 8) {
            float4 v[8];
#pragma unroll
            for (int j = 0; j < 8; ++j)
                v[j] = *(const float4*)(Vb + (size_t)(l0 + j) * HD);
#pragma unroll
            for (int i = 0; i < 3; ++i) {
                int u = ug4 + 16 * i;
                if (u < UU) {
                    float4 pa = *(const float4*)(&PT[u][l0]);
                    float4 pb = *(const float4*)(&PT[u][l0 + 4]);
                    acc[i].x += pa.x * v[0].x + pa.y * v[1].x + pa.z * v[2].x + pa.w * v[3].x
                              + pb.x * v[4].x + pb.y * v[5].x + pb.z * v[6].x + pb.w * v[7].x;
                    acc[i].y += pa.x * v[0].y + pa.y * v[1].y + pa.z * v[2].y + pa.w * v[3].y
                              + pb.x * v[4].y + pb.y * v[5].y + pb.z * v[6].y + pb.w * v[7].y;
                    acc[i].z += pa.x * v[0].z + pa.y * v[1].z + pa.z * v[2].z + pa.w * v[3].z
                              + pb.x * v[4].z + pb.y * v[5].z + pb.z * v[6].z + pb.w * v[7].z;
                    acc[i].w += pa.x * v[0].w + pa.y * v[1].w + pa.z * v[2].w + pa.w * v[3].w
                              + pb.x * v[4].w + pb.y * v[5].w + pb.z * v[6].w + pb.w * v[7].w;
                }
            }
        }
#pragma unroll
        for (int i = 0; i < 3; ++i) {
            int u = ug4 + 16 * i;
            if (u < UU) {
                size_t ob = (((size_t)(bh * UU + u)) * NCHUNK + c) * DD + dq * 4;
                *(float4*)(Opart + ob) = acc[i];
            }
        }
    }
    // mred/sred were written before the barrier above -> safe to read now
    if (tid < UU) {
        mpart[(bh * UU + tid) * NCHUNK + c] = mred[tid];
        spart[(bh * UU + tid) * NCHUNK + c] = sred[tid];
    }
}

// ============ kernel F: combine chunk partials, scatter into output ============
__global__ __launch_bounds__(64) void kF_combine(
    const float* __restrict__ Opart, const float* __restrict__ mpart,
    const float* __restrict__ spart, const int* __restrict__ TopIdx,
    float* __restrict__ out)
{
    int g = blockIdx.x;            // bh*40 + u
    int bh = g / UU;
    int b = bh >> 3, h = bh & 7;
    int d = threadIdx.x;

    float m_i[NCHUNK];
    float Mx = -1e30f;
#pragma unroll
    for (int i = 0; i < NCHUNK; ++i) { m_i[i] = mpart[g * NCHUNK + i]; Mx = fmaxf(Mx, m_i[i]); }
    float S = 0.f, O = 0.f;
#pragma unroll
    for (int i = 0; i < NCHUNK; ++i) {
        float w = __expf(m_i[i] - Mx);
        S += w * spart[g * NCHUNK + i];
        O += w * Opart[((size_t)g * NCHUNK + i) * DD + d];
    }
    int qi = TopIdx[g];
    out[((size_t)b * LL + qi) * HD + h * DD + d] = O / S;
}

extern "C" void kernel_launch(void* const* d_in, const int* in_sizes, int n_in,
                              void* d_out, int out_size, void* d_ws, size_t ws_size,
                              hipStream_t stream) {
    const float* Q  = (const float*)d_in[0];
    const float* K  = (const float*)d_in[1];
    const float* V  = (const float*)d_in[2];
    const int*   IS = (const int*)d_in[3];
    float* out = (float*)d_out;
    char* ws = (char*)d_ws;

    float* M      = (float*)(ws + OFF_M);
    int*   TopIdx = (int*)(ws + OFF_TOP);
    float* Vpart  = (float*)(ws + OFF_VPART);
    float* mpart  = (float*)(ws + OFF_MPART);
    float* spart  = (float*)(ws + OFF_SPART);
    float* Opart  = (float*)(ws + OFF_OPART);

    kA_sample_scores<<<BB * LL, 128, 0, stream>>>(Q, K, IS, M);
    kC_vmean<<<BB * HH * 8, 256, 0, stream>>>(V, Vpart);
    kB_topk<<<BB * HH, 256, 0, stream>>>(M, TopIdx);
    kD_fill<<<(BB * LL * HD) / (256 * 4), 256, 0, stream>>>(Vpart, out);
    kE_attn_partial<<<dim3(NCHUNK, BB * HH), 256, 0, stream>>>(Q, K, V, TopIdx,
                                                               Opart, mpart, spart);
    kF_combine<<<BB * HH * UU, 64, 0, stream>>>(Opart, mpart, spart, TopIdx, out);
}

// Round 3
// 245.190 us; speedup vs baseline: 1.5180x; 1.5180x over previous
//
#include <hip/hip_runtime.h>
#include <hip/hip_bf16.h>

// Problem constants (B,L,H,D) = (8,2048,8,64); sample_k = u = 40.
#define BB 8
#define LL 2048
#define HH 8
#define DD 64
#define HD 512      // H*D
#define SK 40       // sample_k
#define UU 40       // top-u
#define NCHUNK 16   // key chunks for flash-decode
#define CHUNK 128   // keys per chunk

typedef float v4f __attribute__((ext_vector_type(4)));

// ---------------- workspace layout (bytes) ----------------
static const size_t OFF_M     = 0;                 // B*H*L floats   = 512 KB
static const size_t OFF_TOP   = 512ull * 1024;     // B*H*40 ints    = 10 KB
static const size_t OFF_VPART = 592ull * 1024;     // 8*B*H*64 floats= 128 KB
static const size_t OFF_MPART = 768ull * 1024;     // B*H*40*16      = 160 KB
static const size_t OFF_SPART = 960ull * 1024;     // B*H*40*16      = 160 KB
static const size_t OFF_OPART = 1152ull * 1024;    // B*H*40*16*64   = 10 MB

// butterfly-add via DPP (VALU pipe). ctrl must be an ICE -> template param.
template <int CTRL>
__device__ __forceinline__ float dpp_add(float x) {
    int yi = __builtin_amdgcn_mov_dpp(__float_as_int(x), CTRL, 0xF, 0xF, true);
    return x + __int_as_float(yi);
}

// ============ kernel A v4: M[b,h,q] = max_s - mean_s of Q.Ksample ============
// block = 128 = 8 heads x 16 lanes. v4: all 40 indices hoisted to SGPRs up
// front (no per-iteration idx->addr->load chain), explicit 10-deep register
// rotation so 10 K-row gathers stay in flight, launch_bounds(128,4) to raise
// the VGPR cap (v3.1's 52 VGPRs collapsed the pipeline to ~2 loads deep).
#define KA_PF 10
__global__ __launch_bounds__(128, 4) void kA_sample_scores(
    const float* __restrict__ Q, const float* __restrict__ K,
    const int* __restrict__ IS, float* __restrict__ M)
{
    int blk = blockIdx.x;
    int b = blk & 7;                 // XCD pin: batch b -> XCD b (K[b]=4MB==L2)
    int q = blk >> 3;
    int tid = threadIdx.x;
    int h = tid >> 4;
    int lane = tid & 15;

    const int* __restrict__ isq = IS + q * SK;   // block-uniform
    size_t base = (size_t)b * LL * HD;
    int off = h * DD + lane * 4;                 // per-thread, constant over s
    v4f qv = __builtin_nontemporal_load(
        (const v4f*)(Q + base + (size_t)q * HD + off));
    const float* __restrict__ Kb = K + base;

    // hoist all 40 indices into SGPRs (batched scalar loads, issued once)
    int sidx[SK];
#pragma unroll
    for (int s = 0; s < SK; ++s)
        sidx[s] = __builtin_amdgcn_readfirstlane(isq[s]);

    // prologue: fill 10-deep rotation buffer
    float4 kv[KA_PF];
#pragma unroll
    for (int i = 0; i < KA_PF; ++i)
        kv[i] = *(const float4*)(Kb + (size_t)sidx[i] * HD + off);

    float mx = -1e30f, sm = 0.f;
#pragma unroll
    for (int s = 0; s < SK; ++s) {
        float4 k = kv[s % KA_PF];
        if (s + KA_PF < SK)
            kv[s % KA_PF] = *(const float4*)(Kb + (size_t)sidx[s + KA_PF] * HD + off);
        float p = qv.x * k.x + qv.y * k.y + qv.z * k.z + qv.w * k.w;
        p = dpp_add<0xB1>(p);    // quad_perm xor1
        p = dpp_add<0x4E>(p);    // quad_perm xor2
        p = dpp_add<0x141>(p);   // row_half_mirror (== xor4 here)
        p = dpp_add<0x140>(p);   // row_mirror      (== xor8 here)
        mx = fmaxf(mx, p);
        sm += p;
    }
    if (lane == 0)
        M[((size_t)(b * HH + h)) * LL + q] = mx - sm * (1.0f / SK);
}

// ============ kernel B: top-40 of M[bh,:] via 3-level parallel radix select ============
__global__ __launch_bounds__(256) void kB_topk(
    const float* __restrict__ M, int* __restrict__ TopIdx)
{
    int bh = blockIdx.x;
    int tid = threadIdx.x;
    __shared__ unsigned keys[LL];        // 8 KB
    __shared__ int      hist[4096];      // 16 KB
    __shared__ int      sscan[256];      // 1 KB
    __shared__ unsigned ckeyA[2048];     // 8 KB
    __shared__ int      cidxA[2048];     // 8 KB
    __shared__ unsigned ckeyB[2048];     // 8 KB
    __shared__ int      cidxB[2048];     // 8 KB
    __shared__ int ctr[8]; // 0:sel 1:nA 2:nB 3:T 4:kprime 5:nExact

    const float* __restrict__ m = M + (size_t)bh * LL;
    for (int i = tid; i < 4096; i += 256) hist[i] = 0;
    if (tid < 8) ctr[tid] = 0;
    __syncthreads();

    // ---- L1 histogram (bits 31:20) ----
    for (int i = tid; i < LL; i += 256) {
        unsigned u = __float_as_uint(m[i]);
        u = (u & 0x80000000u) ? ~u : (u | 0x80000000u);   // monotone key
        keys[i] = u;
        atomicAdd(&hist[u >> 20], 1);
    }
    __syncthreads();
    // ---- L1 scan (target UU) ----
    {
        int p = 0;
#pragma unroll
        for (int j = 0; j < 16; ++j) p += hist[tid * 16 + j];
        sscan[tid] = p;
        __syncthreads();
        for (int o = 1; o < 256; o <<= 1) {
            int v = (tid + o < 256) ? sscan[tid + o] : 0;
            __syncthreads();
            sscan[tid] += v;
            __syncthreads();
        }
        int snext = (tid < 255) ? sscan[tid + 1] : 0;
        if (sscan[tid] >= UU && snext < UU) {
            int cum = snext;
            for (int bkt = tid * 16 + 15; bkt >= tid * 16; --bkt) {
                int c = hist[bkt];
                if (cum + c >= UU) { ctr[3] = bkt; ctr[4] = UU - cum; break; }
                cum += c;
            }
        }
    }
    __syncthreads();
    unsigned T1 = (unsigned)ctr[3];
    int k1 = ctr[4];
    // ---- L1 pass ----
    for (int i = tid; i < LL; i += 256) {
        unsigned u = keys[i];
        unsigned bkt = u >> 20;
        if (bkt > T1) {
            int p = atomicAdd(&ctr[0], 1);
            TopIdx[bh * UU + p] = i;
        } else if (bkt == T1) {
            int p = atomicAdd(&ctr[1], 1);
            ckeyA[p] = u; cidxA[p] = i;
        }
    }
    __syncthreads();
    int nA = ctr[1];

    // ---- L2 histogram (bits 19:8) ----
    for (int i = tid; i < 4096; i += 256) hist[i] = 0;
    __syncthreads();
    for (int i = tid; i < nA; i += 256)
        atomicAdd(&hist[(ckeyA[i] >> 8) & 0xFFF], 1);
    __syncthreads();
    // ---- L2 scan (target k1) ----
    {
        int p = 0;
#pragma unroll
        for (int j = 0; j < 16; ++j) p += hist[tid * 16 + j];
        sscan[tid] = p;
        __syncthreads();
        for (int o = 1; o < 256; o <<= 1) {
            int v = (tid + o < 256) ? sscan[tid + o] : 0;
            __syncthreads();
            sscan[tid] += v;
            __syncthreads();
        }
        int snext = (tid < 255) ? sscan[tid + 1] : 0;
        if (sscan[tid] >= k1 && snext < k1) {
            int cum = snext;
            for (int bkt = tid * 16 + 15; bkt >= tid * 16; --bkt) {
                int c = hist[bkt];
                if (cum + c >= k1) { ctr[3] = bkt; ctr[4] = k1 - cum; break; }
                cum += c;
            }
        }
    }
    __syncthreads();
    unsigned T2 = (unsigned)ctr[3];
    int k2 = ctr[4];
    // ---- L2 pass ----
    for (int i = tid; i < nA; i += 256) {
        unsigned u = ckeyA[i];
        unsigned bkt = (u >> 8) & 0xFFF;
        if (bkt > T2) {
            int p = atomicAdd(&ctr[0], 1);
            TopIdx[bh * UU + p] = cidxA[i];
        } else if (bkt == T2) {
            int p = atomicAdd(&ctr[2], 1);
            ckeyB[p] = u; cidxB[p] = cidxA[i];
        }
    }
    __syncthreads();
    int nB = ctr[2];

    // ---- L3 histogram (bits 7:0) ----
    for (int i = tid; i < 256; i += 256) hist[i] = 0;
    __syncthreads();
    for (int i = tid; i < nB; i += 256)
        atomicAdd(&hist[ckeyB[i] & 0xFF], 1);
    __syncthreads();
    // ---- L3 scan (target k2) ----
    {
        sscan[tid] = hist[tid];
        __syncthreads();
        for (int o = 1; o < 256; o <<= 1) {
            int v = (tid + o < 256) ? sscan[tid + o] : 0;
            __syncthreads();
            sscan[tid] += v;
            __syncthreads();
        }
        int snext = (tid < 255) ? sscan[tid + 1] : 0;
        if (sscan[tid] >= k2 && snext < k2) { ctr[3] = tid; ctr[4] = k2 - snext; }
    }
    __syncthreads();
    unsigned T3 = (unsigned)ctr[3];
    int k3 = ctr[4];
    // ---- L3 pass ----
    for (int i = tid; i < nB; i += 256) {
        unsigned u = ckeyB[i];
        unsigned bkt = u & 0xFF;
        if (bkt > T3) {
            int p = atomicAdd(&ctr[0], 1);
            TopIdx[bh * UU + p] = cidxB[i];
        } else if (bkt == T3) {
            int p = atomicAdd(&ctr[5], 1);
            cidxA[p] = cidxB[i];
        }
    }
    __syncthreads();
    // ---- exact-key ties: pick k3 smallest indices ----
    if (tid == 0) {
        int n = ctr[5];
        int basep = ctr[0];
        for (int r = 0; r < k3; ++r) {
            int bi = 1 << 30, bp = -1;
            for (int j = 0; j < n; ++j) {
                int id = cidxA[j];
                if (id >= 0 && id < bi) { bi = id; bp = j; }
            }
            TopIdx[bh * UU + basep + r] = bi;
            cidxA[bp] = -1;
        }
    }
}

// ============ kernel C: V partial column-sums (float4 coalesced) ============
__global__ __launch_bounds__(256) void kC_vmean(
    const float* __restrict__ V, float* __restrict__ Vpart)
{
    int bh = blockIdx.x >> 3;
    int ch = blockIdx.x & 7;
    int b = bh >> 3, h = bh & 7;
    int tid = threadIdx.x;
    int dq = tid & 15;
    int lg = tid >> 4;

    float4 acc = make_float4(0.f, 0.f, 0.f, 0.f);
    size_t base = ((size_t)b * LL + ch * 256) * HD + h * DD + dq * 4;
    for (int l = lg; l < 256; l += 16) {
        float4 v = *(const float4*)(V + base + (size_t)l * HD);
        acc.x += v.x; acc.y += v.y; acc.z += v.z; acc.w += v.w;
    }
    __shared__ float4 red[256];
    red[tid] = acc;
    __syncthreads();
    if (tid < 16) {
        float4 s = make_float4(0.f, 0.f, 0.f, 0.f);
#pragma unroll
        for (int g = 0; g < 16; ++g) {
            float4 v = red[g * 16 + tid];
            s.x += v.x; s.y += v.y; s.z += v.z; s.w += v.w;
        }
        *(float4*)(Vpart + ch * 4096 + bh * 64 + tid * 4) = s;
    }
}

// ============ kernel D: fill all output rows with mean(V)/L ============
__global__ __launch_bounds__(256) void kD_fill(
    const float* __restrict__ Vpart, float* __restrict__ out)
{
    size_t i4 = (size_t)blockIdx.x * 256 + threadIdx.x;
    size_t o = i4 * 4;
    int hd = (int)(o & (HD - 1));
    int b  = (int)(o >> 20);
    int h  = hd >> 6;
    int idx = (b * HH + h) * DD + (hd & 63);
    float4 acc = make_float4(0.f, 0.f, 0.f, 0.f);
#pragma unroll
    for (int c = 0; c < 8; ++c) {
        float4 v = *(const float4*)(Vpart + c * 4096 + idx);
        acc.x += v.x; acc.y += v.y; acc.z += v.z; acc.w += v.w;
    }
    const float sc = 1.0f / LL;
    float4 r; r.x = acc.x * sc; r.y = acc.y * sc; r.z = acc.z * sc; r.w = acc.w * sc;
    *(float4*)(out + o) = r;
}

// ============ kernel E v7: flash-decode partials ============
// v6's LDS scheme (P transposed -> b128 PV reads; 2-key-rows/thread scores;
// single-wave softmax butterfly) was sound (bank conflicts = 0), but fully
// unrolling the qt loop hoisted 32 float4 K-loads -> VGPR=256 -> occupancy
// 11% -> 193us. v7: `#pragma unroll 1` on qt (one iteration's 32 K-VGPRs
// live at a time) + __launch_bounds__(256,4) caps VGPR at 128 so we get
// 4 blocks/CU (16 waves, 50% occupancy; LDS at 31.5KB allows 5).
__global__ __launch_bounds__(256, 4) void kE_attn_partial(
    const float* __restrict__ Q, const float* __restrict__ K, const float* __restrict__ V,
    const int* __restrict__ TopIdx,
    float* __restrict__ Opart, float* __restrict__ mpart, float* __restrict__ spart)
{
    int c  = blockIdx.x;
    int bh = blockIdx.y;
    int b = bh >> 3, h = bh & 7;
    int tid = threadIdx.x;

    __shared__ float Qs[UU * DD];            // 10 KB
    __shared__ float PT[UU][CHUNK + 4];      // 20.6 KB, transposed P, stride 132
    __shared__ int   qidx[UU];
    __shared__ float mred[UU], sred[UU];

    if (tid < UU) qidx[tid] = TopIdx[bh * UU + tid];
    __syncthreads();

    size_t hbase  = (size_t)b * LL * HD + h * DD;
    size_t kcbase = hbase + (size_t)c * CHUNK * HD;

    for (int r = tid; r < UU * 16; r += 256) {
        int u = r >> 4, j = r & 15;
        *(float4*)(Qs + u * DD + j * 4) =
            *(const float4*)(Q + hbase + (size_t)qidx[u] * HD + j * 4);
    }
    __syncthreads();

    // ---- scores + in-register softmax ----
    {
        int w = tid >> 6;            // wave id: owns u in [w*10, w*10+10)
        int lane = tid & 63;         // key rows l0=lane, l1=lane+64
        const float* __restrict__ K0 = K + kcbase + (size_t)lane * HD;
        const float* __restrict__ K1 = K0 + (size_t)64 * HD;

        float d0[10], d1[10];
#pragma unroll
        for (int i = 0; i < 10; ++i) { d0[i] = 0.f; d1[i] = 0.f; }

#pragma unroll 1
        for (int qt = 0; qt < 4; ++qt) {        // 16 floats of d per quarter
            float4 ka[4], kb[4];
#pragma unroll
            for (int j = 0; j < 4; ++j) {
                ka[j] = *(const float4*)(K0 + qt * 16 + j * 4);
                kb[j] = *(const float4*)(K1 + qt * 16 + j * 4);
            }
#pragma unroll
            for (int j = 0; j < 4; ++j) {
#pragma unroll
                for (int uu = 0; uu < 10; ++uu) {
                    float4 qv = *(const float4*)(Qs + (w * 10 + uu) * DD + qt * 16 + j * 4);
                    d0[uu] += qv.x * ka[j].x + qv.y * ka[j].y + qv.z * ka[j].z + qv.w * ka[j].w;
                    d1[uu] += qv.x * kb[j].x + qv.y * kb[j].y + qv.z * kb[j].z + qv.w * kb[j].w;
                }
            }
        }

#pragma unroll
        for (int uu = 0; uu < 10; ++uu) {
            int u = w * 10 + uu;
            float x0 = d0[uu] * 0.125f;          // 1/sqrt(64)
            float x1 = d1[uu] * 0.125f;
            float m = fmaxf(x0, x1);
            m = fmaxf(m, __shfl_xor(m, 1));
            m = fmaxf(m, __shfl_xor(m, 2));
            m = fmaxf(m, __shfl_xor(m, 4));
            m = fmaxf(m, __shfl_xor(m, 8));
            m = fmaxf(m, __shfl_xor(m, 16));
            m = fmaxf(m, __shfl_xor(m, 32));     // max over all 128 keys
            float p0 = __expf(x0 - m);
            float p1 = __expf(x1 - m);
            PT[u][lane]      = p0;
            PT[u][lane + 64] = p1;
            float s = p0 + p1;
            s += __shfl_xor(s, 1);
            s += __shfl_xor(s, 2);
            s += __shfl_xor(s, 4);
            s += __shfl_xor(s, 8);
            s += __shfl_xor(s, 16);
            s += __shfl_xor(s, 32);              // sum over all 128 keys
            if (lane == 0) { mred[u] = m; sred[u] = s; }
        }
    }
    __syncthreads();   // PT + mred/sred ready

    // ---- PV: thread (dq = tid&15 -> d=dq*4, ug4 = tid>>4); u = ug4 + 16i ----
    {
        int dq = tid & 15, ug4 = tid >> 4;
        float4 acc[3];
#pragma unroll
        for (int i = 0; i < 3; ++i) acc[i] = make_float4(0.f, 0.f, 0.f, 0.f);
        const float* __restrict__ Vb = V + kcbase + dq * 4;
        for (int l0 = 0; l0 < CHUNK; l0 += 8) {
            float4 v[8];
#pragma unroll
            for (int j = 0; j < 8; ++j)
                v[j] = *(const float4*)(Vb + (size_t)(l0 + j) * HD);
#pragma unroll
            for (int i = 0; i < 3; ++i) {
                int u = ug4 + 16 * i;
                if (u < UU) {
                    float4 pa = *(const float4*)(&PT[u][l0]);
                    float4 pb = *(const float4*)(&PT[u][l0 + 4]);
                    acc[i].x += pa.x * v[0].x + pa.y * v[1].x + pa.z * v[2].x + pa.w * v[3].x
                              + pb.x * v[4].x + pb.y * v[5].x + pb.z * v[6].x + pb.w * v[7].x;
                    acc[i].y += pa.x * v[0].y + pa.y * v[1].y + pa.z * v[2].y + pa.w * v[3].y
                              + pb.x * v[4].y + pb.y * v[5].y + pb.z * v[6].y + pb.w * v[7].y;
                    acc[i].z += pa.x * v[0].z + pa.y * v[1].z + pa.z * v[2].z + pa.w * v[3].z
                              + pb.x * v[4].z + pb.y * v[5].z + pb.z * v[6].z + pb.w * v[7].z;
                    acc[i].w += pa.x * v[0].w + pa.y * v[1].w + pa.z * v[2].w + pa.w * v[3].w
                              + pb.x * v[4].w + pb.y * v[5].w + pb.z * v[6].w + pb.w * v[7].w;
                }
            }
        }
#pragma unroll
        for (int i = 0; i < 3; ++i) {
            int u = ug4 + 16 * i;
            if (u < UU) {
                size_t ob = (((size_t)(bh * UU + u)) * NCHUNK + c) * DD + dq * 4;
                *(float4*)(Opart + ob) = acc[i];
            }
        }
    }
    // mred/sred were written before the barrier above -> safe to read now
    if (tid < UU) {
        mpart[(bh * UU + tid) * NCHUNK + c] = mred[tid];
        spart[(bh * UU + tid) * NCHUNK + c] = sred[tid];
    }
}

// ============ kernel F: combine chunk partials, scatter into output ============
__global__ __launch_bounds__(64) void kF_combine(
    const float* __restrict__ Opart, const float* __restrict__ mpart,
    const float* __restrict__ spart, const int* __restrict__ TopIdx,
    float* __restrict__ out)
{
    int g = blockIdx.x;            // bh*40 + u
    int bh = g / UU;
    int b = bh >> 3, h = bh & 7;
    int d = threadIdx.x;

    float m_i[NCHUNK];
    float Mx = -1e30f;
#pragma unroll
    for (int i = 0; i < NCHUNK; ++i) { m_i[i] = mpart[g * NCHUNK + i]; Mx = fmaxf(Mx, m_i[i]); }
    float S = 0.f, O = 0.f;
#pragma unroll
    for (int i = 0; i < NCHUNK; ++i) {
        float w = __expf(m_i[i] - Mx);
        S += w * spart[g * NCHUNK + i];
        O += w * Opart[((size_t)g * NCHUNK + i) * DD + d];
    }
    int qi = TopIdx[g];
    out[((size_t)b * LL + qi) * HD + h * DD + d] = O / S;
}

extern "C" void kernel_launch(void* const* d_in, const int* in_sizes, int n_in,
                              void* d_out, int out_size, void* d_ws, size_t ws_size,
                              hipStream_t stream) {
    const float* Q  = (const float*)d_in[0];
    const float* K  = (const float*)d_in[1];
    const float* V  = (const float*)d_in[2];
    const int*   IS = (const int*)d_in[3];
    float* out = (float*)d_out;
    char* ws = (char*)d_ws;

    float* M      = (float*)(ws + OFF_M);
    int*   TopIdx = (int*)(ws + OFF_TOP);
    float* Vpart  = (float*)(ws + OFF_VPART);
    float* mpart  = (float*)(ws + OFF_MPART);
    float* spart  = (float*)(ws + OFF_SPART);
    float* Opart  = (float*)(ws + OFF_OPART);

    kA_sample_scores<<<BB * LL, 128, 0, stream>>>(Q, K, IS, M);
    kC_vmean<<<BB * HH * 8, 256, 0, stream>>>(V, Vpart);
    kB_topk<<<BB * HH, 256, 0, stream>>>(M, TopIdx);
    kD_fill<<<(BB * LL * HD) / (256 * 4), 256, 0, stream>>>(Vpart, out);
    kE_attn_partial<<<dim3(NCHUNK, BB * HH), 256, 0, stream>>>(Q, K, V, TopIdx,
                                                               Opart, mpart, spart);
    kF_combine<<<BB * HH * UU, 64, 0, stream>>>(Opart, mpart, spart, TopIdx, out);
}